// Round 2
// baseline (148.817 us; speedup 1.0000x reference)
//
#include <hip/hip_runtime.h>
#include <hip/hip_bf16.h>
#include <stdint.h>

// Problem constants (fixed by reference)
#define BB 4
#define LL 256
#define WW 256
#define HH 768
#define TL 4            // L-rows per block
#define HC 64           // h-chunk (floats) staged in LDS per iteration
#define NCH 12          // 768 / 64
#define NL 10           // num labels

typedef __attribute__((address_space(3))) uint32_t lds_u32_t;
typedef __attribute__((address_space(1))) uint32_t glb_u32_t;

__global__ __launch_bounds__(256, 1) void wordkvmn_kernel(
    const int* __restrict__ word_seq,   // [B,W] int32
    const float* __restrict__ hidden,   // [B,L,H]
    const int* __restrict__ label,      // [B,L,W] int32
    const float* __restrict__ mask,     // [B,L,W]
    const float* __restrict__ emb_a,    // [50000,H]
    const float* __restrict__ emb_c,    // [10,H]
    float* __restrict__ out)            // [B,L,H]
{
    // Double-buffered gathered emb_a chunk: [256 rows][64 floats], rotation-
    // swizzled at float4 granularity. LDS dest of global_load_lds is linear
    // (HW requirement); the swizzle is applied on the SOURCE address and on
    // the read side (both-sides-or-neither).
    __shared__ float buf[2][WW * HC];   // 2 x 64 KiB = 128 KiB
    __shared__ float s_lds[TL][NL];
    __shared__ float red[TL][4];

    const int t   = threadIdx.x;
    const int bid = blockIdx.x;
    const int b   = bid >> 6;           // / (L/TL)
    const int l0  = (bid & 63) * TL;

    if (t < TL * NL) ((float*)s_lds)[t] = 0.0f;

    // Per-thread byte offsets into emb_a for the 16 staging slots (chunk 0).
    // Linear LDS slot q = p*256 + t  ->  row w = q>>4, stored col4 jp = q&15,
    // which must hold data col4 j = (jp - w) & 15 of the chunk.
    uint32_t voff[16];
    #pragma unroll
    for (int p = 0; p < 16; ++p) {
        int q   = p * 256 + t;
        int w   = q >> 4;
        int jp  = q & 15;
        int j   = (jp - w) & 15;
        int row = word_seq[b * WW + w];
        voff[p] = (uint32_t)row * (HH * 4) + (uint32_t)j * 16;
    }

    const char*  ea_base = (const char*)emb_a;
    const float* hb = hidden + ((size_t)b * LL + l0) * HH;  // block-uniform

    float u[TL] = {0.f, 0.f, 0.f, 0.f};

    // Prologue: stage chunk 0 into buf[0]
    #pragma unroll
    for (int p = 0; p < 16; ++p) {
        __builtin_amdgcn_global_load_lds(
            (const glb_u32_t*)(ea_base + voff[p]),
            (lds_u32_t*)&buf[0][(p * 256 + t) * 4], 16, 0, 0);
    }

    #pragma unroll
    for (int c = 0; c < NCH; ++c) {
        // Chunk c's DMA writes landed (own vmcnt) + all waves past compute(c-1).
        asm volatile("s_waitcnt vmcnt(0)" ::: "memory");
        __builtin_amdgcn_s_barrier();
        asm volatile("" ::: "memory");

        // Prefetch chunk c+1 into the other buffer (safe: nobody reads it now,
        // and every wave has finished reading it for compute(c-1)).
        if (c + 1 < NCH) {
            #pragma unroll
            for (int p = 0; p < 16; ++p) {
                __builtin_amdgcn_global_load_lds(
                    (const glb_u32_t*)(ea_base + voff[p] + (c + 1) * (HC * 4 / 16) * 16),
                    (lds_u32_t*)&buf[(c + 1) & 1][(p * 256 + t) * 4], 16, 0, 0);
            }
        }

        // Compute: thread t owns ea row w=t; hidden comes from the scalar
        // pipe (wave-uniform address -> s_load), no LDS for it.
        const float* bc = buf[c & 1];
        #pragma unroll
        for (int j = 0; j < 16; ++j) {
            int jp = (j + t) & 15;                       // rotation swizzle
            float4 e = *(const float4*)&bc[(t * 16 + jp) * 4];
            #pragma unroll
            for (int l = 0; l < TL; ++l) {
                float4 h = *(const float4*)&hb[l * HH + c * HC + j * 4]; // uniform
                u[l] = fmaf(h.x, e.x, u[l]);
                u[l] = fmaf(h.y, e.y, u[l]);
                u[l] = fmaf(h.z, e.z, u[l]);
                u[l] = fmaf(h.w, e.w, u[l]);
            }
        }
    }

    // ---- masked exp ----
    const float scale = 0.03608439182435161f;  // 1/sqrt(768)
    float e[TL];
    const size_t mbase = ((size_t)b * LL + l0) * WW + t;
    #pragma unroll
    for (int l = 0; l < TL; ++l) {
        float m = mask[mbase + (size_t)l * WW];
        m = fminf(fmaxf(m, 0.f), 1.f);
        e[l] = __expf(u[l] * scale) * m;
    }

    // ---- softmax denominator: reduce over 256 threads per l ----
    const int lane = t & 63, wid = t >> 6;
    #pragma unroll
    for (int l = 0; l < TL; ++l) {
        float r = e[l];
        #pragma unroll
        for (int off = 32; off; off >>= 1) r += __shfl_xor(r, off, 64);
        if (lane == 0) red[l][wid] = r;
    }
    __syncthreads();

    float p[TL];
    #pragma unroll
    for (int l = 0; l < TL; ++l) {
        float sum = red[l][0] + red[l][1] + red[l][2] + red[l][3] + 1e-10f;
        p[l] = e[l] / sum;
    }

    // ---- bucket p by label (emb_c has only 10 rows) ----
    #pragma unroll
    for (int l = 0; l < TL; ++l) {
        int k = label[mbase + (size_t)l * WW];
        atomicAdd(&s_lds[l][k], p[l]);
    }
    __syncthreads();

    // ---- epilogue: o[l,h] = hidden[l,h] + sum_k s[l][k] * emb_c[k,h] ----
    #pragma unroll
    for (int j = 0; j < 3; ++j) {
        int h = j * 256 + t;
        float ec[NL];
        #pragma unroll
        for (int k = 0; k < NL; ++k) ec[k] = emb_c[k * HH + h];
        #pragma unroll
        for (int l = 0; l < TL; ++l) {
            size_t base = ((size_t)b * LL + l0 + l) * HH + h;
            float acc = hidden[base];
            #pragma unroll
            for (int k = 0; k < NL; ++k) acc = fmaf(s_lds[l][k], ec[k], acc);
            out[base] = acc;
        }
    }
}

extern "C" void kernel_launch(void* const* d_in, const int* in_sizes, int n_in,
                              void* d_out, int out_size, void* d_ws, size_t ws_size,
                              hipStream_t stream) {
    const int*   word_seq = (const int*)d_in[0];
    const float* hidden   = (const float*)d_in[1];
    const int*   label    = (const int*)d_in[2];
    const float* mask     = (const float*)d_in[3];
    const float* emb_a    = (const float*)d_in[4];
    const float* emb_c    = (const float*)d_in[5];
    float*       out      = (float*)d_out;

    wordkvmn_kernel<<<BB * (LL / TL), 256, 0, stream>>>(
        word_seq, hidden, label, mask, emb_a, emb_c, out);
}

// Round 3
// 44.221 us; speedup vs baseline: 3.3653x; 3.3653x over previous
//
#include <hip/hip_runtime.h>
#include <hip/hip_bf16.h>
#include <stdint.h>

// Problem constants (fixed by reference)
#define BB 4
#define LL 256
#define WW 256
#define HH 768
#define TL 4            // L-rows per block
#define HC 48           // h-chunk staged in LDS
#define NCH (HH / HC)   // 16 chunks
#define EPAD 52         // ea_s row stride in floats: 208B, conflict-free for stride reads
#define NL 10           // num labels

// ---------------------------------------------------------------------------
// Kernel 1: gather emb_a rows into a compact, L2-resident table
//   ea_g[b][w][h] = emb_a[word_seq[b][w]][h]   (fp32, 4*256*768*4B = 3.1 MB)
// 768 blocks x 256 threads, one float4 per thread.
// ---------------------------------------------------------------------------
__global__ __launch_bounds__(256) void gather_kernel(
    const int* __restrict__ word_seq,   // [B*W] flat = 1024
    const float* __restrict__ emb_a,    // [50000,H]
    float* __restrict__ ea_g)           // [B*W, H]
{
    const int i  = blockIdx.x * 256 + threadIdx.x;  // [0, 196608)
    const int r  = i / 192;                         // gathered row [0,1024)
    const int c4 = i - r * 192;                     // float4 column [0,192)
    const int row = word_seq[r];
    reinterpret_cast<float4*>(ea_g)[(size_t)r * 192 + c4] =
        reinterpret_cast<const float4*>(emb_a)[(size_t)row * 192 + c4];
}

// ---------------------------------------------------------------------------
// Kernel 2: fused u-GEMM + masked softmax + label-bucketing + 10-row epilogue
// Reads ea_g (dense, L2-resident) instead of the scattered 153 MB table.
// ---------------------------------------------------------------------------
__global__ __launch_bounds__(256, 2) void wordkvmn_kernel(
    const float* __restrict__ hidden,   // [B,L,H]
    const int* __restrict__ label,      // [B,L,W] int32
    const float* __restrict__ mask,     // [B,L,W]
    const float* __restrict__ ea_g,     // [B,W,H] gathered
    const float* __restrict__ emb_c,    // [10,H]
    float* __restrict__ out)            // [B,L,H]
{
    __shared__ float ea_s[WW][EPAD];    // 53248 B
    __shared__ float s_lds[TL][NL];
    __shared__ float red[TL][4];

    const int t   = threadIdx.x;
    const int bid = blockIdx.x;
    const int b   = bid >> 6;           // / (L/TL)
    const int l0  = (bid & 63) * TL;

    if (t < TL * NL) ((float*)s_lds)[t] = 0.0f;

    const float* eab = ea_g + (size_t)b * WW * HH;          // dense [256][768]
    const float* hb  = hidden + ((size_t)b * LL + l0) * HH; // block-uniform

    float u[TL] = {0.f, 0.f, 0.f, 0.f};

    for (int c = 0; c < NCH; ++c) {
        __syncthreads();  // s_lds zeroed (c==0) / ea_s consumed (c>0)

        // stage dense ea chunk: 256 rows x 48 floats = 2304 float4, 9/thread
        const int base_h = c * HC;
        #pragma unroll
        for (int p = 0; p < 9; ++p) {
            int f   = p * 256 + t;      // [0,2304)
            int w   = f / 12;
            int col = (f % 12) * 4;
            const float4 v = *reinterpret_cast<const float4*>(
                &eab[(size_t)w * HH + base_h + col]);
            *reinterpret_cast<float4*>(&ea_s[w][col]) = v;
        }
        __syncthreads();

        // accumulate u: thread t owns w=t; hidden comes from the scalar pipe
        // (wave-uniform address -> s_load), zero LDS cost.
        #pragma unroll
        for (int hh = 0; hh < HC; hh += 4) {
            float4 e4 = *reinterpret_cast<const float4*>(&ea_s[t][hh]);
            #pragma unroll
            for (int l = 0; l < TL; ++l) {
                float4 h4 = *reinterpret_cast<const float4*>(&hb[l * HH + base_h + hh]);
                u[l] = fmaf(h4.x, e4.x, u[l]);
                u[l] = fmaf(h4.y, e4.y, u[l]);
                u[l] = fmaf(h4.z, e4.z, u[l]);
                u[l] = fmaf(h4.w, e4.w, u[l]);
            }
        }
    }

    // ---- masked exp ----
    const float scale = 0.03608439182435161f;  // 1/sqrt(768)
    float e[TL];
    const size_t mbase = ((size_t)b * LL + l0) * WW + t;
    #pragma unroll
    for (int l = 0; l < TL; ++l) {
        float m = mask[mbase + (size_t)l * WW];
        m = fminf(fmaxf(m, 0.f), 1.f);
        e[l] = __expf(u[l] * scale) * m;
    }

    // ---- softmax denominator: reduce over 256 threads per l ----
    const int lane = t & 63, wid = t >> 6;
    #pragma unroll
    for (int l = 0; l < TL; ++l) {
        float r = e[l];
        #pragma unroll
        for (int off = 32; off; off >>= 1) r += __shfl_xor(r, off, 64);
        if (lane == 0) red[l][wid] = r;
    }
    __syncthreads();

    float p[TL];
    #pragma unroll
    for (int l = 0; l < TL; ++l) {
        float sum = red[l][0] + red[l][1] + red[l][2] + red[l][3] + 1e-10f;
        p[l] = e[l] / sum;
    }

    // ---- bucket p by label (emb_c has only 10 rows) ----
    #pragma unroll
    for (int l = 0; l < TL; ++l) {
        int k = label[mbase + (size_t)l * WW];
        atomicAdd(&s_lds[l][k], p[l]);
    }
    __syncthreads();

    // ---- epilogue: o[l,h] = hidden[l,h] + sum_k s[l][k] * emb_c[k,h] ----
    #pragma unroll
    for (int j = 0; j < 3; ++j) {
        int h = j * 256 + t;
        float ec[NL];
        #pragma unroll
        for (int k = 0; k < NL; ++k) ec[k] = emb_c[k * HH + h];
        #pragma unroll
        for (int l = 0; l < TL; ++l) {
            size_t base = ((size_t)b * LL + l0 + l) * HH + h;
            float acc = hidden[base];
            #pragma unroll
            for (int k = 0; k < NL; ++k) acc = fmaf(s_lds[l][k], ec[k], acc);
            out[base] = acc;
        }
    }
}

extern "C" void kernel_launch(void* const* d_in, const int* in_sizes, int n_in,
                              void* d_out, int out_size, void* d_ws, size_t ws_size,
                              hipStream_t stream) {
    const int*   word_seq = (const int*)d_in[0];
    const float* hidden   = (const float*)d_in[1];
    const int*   label    = (const int*)d_in[2];
    const float* mask     = (const float*)d_in[3];
    const float* emb_a    = (const float*)d_in[4];
    const float* emb_c    = (const float*)d_in[5];
    float*       out      = (float*)d_out;
    float*       ea_g     = (float*)d_ws;   // 4*256*768 fp32 = 3.1 MB

    gather_kernel<<<768, 256, 0, stream>>>(word_seq, emb_a, ea_g);
    wordkvmn_kernel<<<BB * (LL / TL), 256, 0, stream>>>(
        hidden, label, mask, ea_g, emb_c, out);
}

// Round 4
// 21.980 us; speedup vs baseline: 6.7707x; 2.0119x over previous
//
#include <hip/hip_runtime.h>
#include <stdint.h>

// Problem constants (fixed by reference)
#define BB 4
#define LL 256
#define WW 256
#define HH 768
#define NL 10
#define LT 16           // L-rows per score block
#define WT 64           // W-cols per score block

typedef __attribute__((ext_vector_type(8))) short bf16x8;   // 8 bf16 (4 VGPRs)
typedef __attribute__((ext_vector_type(4))) float f32x4;    // MFMA C/D

__device__ inline unsigned short f2bf(float x) {            // RNE fp32->bf16
    uint32_t u = __builtin_bit_cast(uint32_t, x);
    return (unsigned short)((u + 0x7FFFu + ((u >> 16) & 1u)) >> 16);
}

// ---------------------------------------------------------------------------
// K1: gather emb_a rows into compact bf16 table + convert hidden to bf16.
//   ea_b [B*W][768] bf16,  hid_b [B*L][768] bf16   (1.5 MB each, L2-resident)
// ---------------------------------------------------------------------------
__global__ __launch_bounds__(256) void prep_kernel(
    const int* __restrict__ word_seq,   // [B*W]
    const float* __restrict__ emb_a,    // [50000,H]
    const float* __restrict__ hidden,   // [B,L,H]
    unsigned short* __restrict__ ea_b,
    unsigned short* __restrict__ hid_b)
{
    const int HALF = BB * WW * (HH / 4);          // 196608 float4 slots
    int i = blockIdx.x * 256 + threadIdx.x;       // [0, 2*HALF)
    if (i < HALF) {
        int r = i / 192, c4 = i - r * 192;
        int row = word_seq[r];
        float4 v = reinterpret_cast<const float4*>(emb_a)[(size_t)row * 192 + c4];
        ushort4 o = { f2bf(v.x), f2bf(v.y), f2bf(v.z), f2bf(v.w) };
        reinterpret_cast<ushort4*>(ea_b)[(size_t)r * 192 + c4] = o;
    } else {
        int j = i - HALF;
        float4 v = reinterpret_cast<const float4*>(hidden)[j];
        ushort4 o = { f2bf(v.x), f2bf(v.y), f2bf(v.z), f2bf(v.w) };
        reinterpret_cast<ushort4*>(hid_b)[j] = o;
    }
}

// ---------------------------------------------------------------------------
// K2: u-tile via MFMA + masked exp + label bucketing.
// Block = (b, 16 L-rows, 64 W-cols); 4 waves, each one 16x16 C-tile.
// Fragments load straight from global (per-lane 16B contiguous, no LDS).
// Writes UNNORMALIZED buckets s[16][10]; denominator D = sum_k s_k later.
// ---------------------------------------------------------------------------
__global__ __launch_bounds__(256, 2) void score_kernel(
    const unsigned short* __restrict__ hid_b,   // [B*L][768] bf16
    const unsigned short* __restrict__ ea_b,    // [B*W][768] bf16
    const int* __restrict__ label,              // [B,L,W]
    const float* __restrict__ mask,             // [B,L,W]
    float* __restrict__ s_out)                  // [256 blocks][16][10]
{
    __shared__ float s_lds[LT][NL];
    const int t    = threadIdx.x;
    const int wave = t >> 6, lane = t & 63;
    const int bid  = blockIdx.x;
    const int wt = bid & 3, lt = (bid >> 2) & 15, b = bid >> 6;
    const int l0 = lt * LT;
    const int g = lane >> 4, c = lane & 15;

    if (t < LT * NL) ((float*)s_lds)[t] = 0.f;

    // A row = lane&15 (M=l), B col = lane&15 (N=w); k-group = lane>>4.
    // A and B use the same (g,elem)->h map, so the pairing is consistent.
    const unsigned short* arow = hid_b + ((size_t)(b * LL) + l0 + c) * HH + g * 8;
    const unsigned short* brow = ea_b  + ((size_t)(b * WW) + wt * WT + wave * 16 + c) * HH + g * 8;

    f32x4 acc = {0.f, 0.f, 0.f, 0.f};
    #pragma unroll
    for (int k = 0; k < 24; ++k) {
        bf16x8 a  = *reinterpret_cast<const bf16x8*>(arow + k * 32);
        bf16x8 bv = *reinterpret_cast<const bf16x8*>(brow + k * 32);
        acc = __builtin_amdgcn_mfma_f32_16x16x32_bf16(a, bv, acc, 0, 0, 0);
    }
    __syncthreads();   // s_lds zeros visible

    // C/D layout (m89): col = lane&15, row = (lane>>4)*4 + reg
    const float scale = 0.03608439182435161f;  // 1/sqrt(768)
    const int wcol = wt * WT + wave * 16 + c;
    #pragma unroll
    for (int r = 0; r < 4; ++r) {
        int lrow = g * 4 + r;
        size_t idx = ((size_t)(b * LL) + l0 + lrow) * WW + wcol;
        float m = mask[idx];
        m = fminf(fmaxf(m, 0.f), 1.f);
        float e = __expf(acc[r] * scale) * m;
        atomicAdd(&s_lds[lrow][label[idx]], e);
    }
    __syncthreads();

    if (t < LT * NL)
        s_out[(size_t)bid * (LT * NL) + t] = ((float*)s_lds)[t];
}

// ---------------------------------------------------------------------------
// K3: combine W-tile partials, normalize, 10-row epilogue + residual.
// Block = (b, 16 L-rows, 192 h-cols); grid 256.
// ---------------------------------------------------------------------------
__global__ __launch_bounds__(256, 4) void combine_kernel(
    const float* __restrict__ s_in,     // [256][16][10]
    const float* __restrict__ hidden,   // [B,L,H]
    const float* __restrict__ emb_c,    // [10,H]
    float* __restrict__ out)            // [B,L,H]
{
    __shared__ float sp[LT][NL];
    __shared__ float inv[LT];
    const int t = threadIdx.x;
    const int bid = blockIdx.x;
    const int hq = bid & 3, lt = (bid >> 2) & 15, b = bid >> 6;
    const int l0 = lt * LT, h0 = hq * 192;

    if (t < LT * NL) {
        size_t base = ((size_t)(b * 16 + lt)) * 4 * (LT * NL);  // wt=0 block
        float v = 0.f;
        #pragma unroll
        for (int wt = 0; wt < 4; ++wt) v += s_in[base + wt * (LT * NL) + t];
        ((float*)sp)[t] = v;
    }
    __syncthreads();
    if (t < LT) {
        float d = 1e-10f;
        #pragma unroll
        for (int k = 0; k < NL; ++k) d += sp[t][k];
        inv[t] = 1.f / d;
    }
    __syncthreads();

    if (t < 192) {
        const int h = h0 + t;
        float ec[NL];
        #pragma unroll
        for (int k = 0; k < NL; ++k) ec[k] = emb_c[k * HH + h];
        #pragma unroll
        for (int r = 0; r < LT; ++r) {
            size_t base = ((size_t)(b * LL) + l0 + r) * HH + h;
            float acc = 0.f;
            #pragma unroll
            for (int k = 0; k < NL; ++k) acc = fmaf(sp[r][k], ec[k], acc);
            out[base] = hidden[base] + acc * inv[r];
        }
    }
}

extern "C" void kernel_launch(void* const* d_in, const int* in_sizes, int n_in,
                              void* d_out, int out_size, void* d_ws, size_t ws_size,
                              hipStream_t stream) {
    const int*   word_seq = (const int*)d_in[0];
    const float* hidden   = (const float*)d_in[1];
    const int*   label    = (const int*)d_in[2];
    const float* mask     = (const float*)d_in[3];
    const float* emb_a    = (const float*)d_in[4];
    const float* emb_c    = (const float*)d_in[5];
    float*       out      = (float*)d_out;

    // Workspace carve (~3.3 MB of 600 MB):
    unsigned short* hid_b = (unsigned short*)d_ws;                 // 1024*768 bf16
    unsigned short* ea_b  = hid_b + (size_t)BB * LL * HH;          // 1024*768 bf16
    float*          s_out = (float*)(ea_b + (size_t)BB * WW * HH); // 256*160 fp32

    prep_kernel<<<1536, 256, 0, stream>>>(word_seq, emb_a, hidden, ea_b, hid_b);
    score_kernel<<<BB * 16 * 4, 256, 0, stream>>>(hid_b, ea_b, label, mask, s_out);
    combine_kernel<<<BB * 16 * 4, 256, 0, stream>>>(s_out, hidden, emb_c, out);
}

// Round 5
// 21.714 us; speedup vs baseline: 6.8535x; 1.0122x over previous
//
#include <hip/hip_runtime.h>
#include <hip/hip_bf16.h>
#include <stdint.h>

// Problem constants (fixed by reference)
#define BB 4
#define LL 256
#define WW 256
#define HH 768
#define NL 10
#define LT 16           // L-rows per score block
#define WT 64           // W-cols per score block

typedef __attribute__((ext_vector_type(8))) short bf16x8;   // 8 bf16 (4 VGPRs)
typedef __attribute__((ext_vector_type(4))) float f32x4;    // MFMA C/D

__device__ inline unsigned short f2bf(float x) {            // RNE via HW cvt
    return __builtin_bit_cast(unsigned short, __float2bfloat16(x));
}
__device__ inline bf16x8 pack8(float4 a, float4 b) {
    union { bf16x8 v; unsigned short u[8]; } r;
    r.u[0] = f2bf(a.x); r.u[1] = f2bf(a.y); r.u[2] = f2bf(a.z); r.u[3] = f2bf(a.w);
    r.u[4] = f2bf(b.x); r.u[5] = f2bf(b.y); r.u[6] = f2bf(b.z); r.u[7] = f2bf(b.w);
    return r.v;
}

// ---------------------------------------------------------------------------
// K1: fused gather + bf16 convert + u-tile MFMA + masked exp + label buckets.
// Block = (b, 16 L-rows, 64 W-cols); 4 waves, each one 16x16 C-tile.
// Fragments load fp32 straight from global (per-lane 2x16B) and convert
// in-register; gathered emb_a rows are L2-resident after first touch.
// Writes UNNORMALIZED buckets s[16][10]; denominator D = sum_k s_k later.
// ---------------------------------------------------------------------------
__global__ __launch_bounds__(256, 2) void score_kernel(
    const int* __restrict__ word_seq,           // [B,W]
    const float* __restrict__ hidden,           // [B,L,H]
    const float* __restrict__ emb_a,            // [50000,H]
    const int* __restrict__ label,              // [B,L,W]
    const float* __restrict__ mask,             // [B,L,W]
    float* __restrict__ s_out)                  // [256 blocks][16][10]
{
    __shared__ float s_lds[LT][NL];
    const int t    = threadIdx.x;
    const int wave = t >> 6, lane = t & 63;
    const int bid  = blockIdx.x;
    const int wt = bid & 3, lt = (bid >> 2) & 15, b = bid >> 6;
    const int l0 = lt * LT;
    const int g = lane >> 4, c = lane & 15;

    if (t < LT * NL) ((float*)s_lds)[t] = 0.f;

    // A row = lane&15 (M=l), B col = lane&15 (N=w); k-group = lane>>4.
    const int wcol = wt * WT + wave * 16 + c;
    const int wrow = word_seq[b * WW + wcol];
    const float* arow = hidden + ((size_t)(b * LL) + l0 + c) * HH + g * 8;
    const float* brow = emb_a + (size_t)wrow * HH + g * 8;

    f32x4 acc = {0.f, 0.f, 0.f, 0.f};
    #pragma unroll
    for (int k = 0; k < 24; ++k) {
        float4 a0 = *reinterpret_cast<const float4*>(arow + k * 32);
        float4 a1 = *reinterpret_cast<const float4*>(arow + k * 32 + 4);
        float4 b0 = *reinterpret_cast<const float4*>(brow + k * 32);
        float4 b1 = *reinterpret_cast<const float4*>(brow + k * 32 + 4);
        acc = __builtin_amdgcn_mfma_f32_16x16x32_bf16(
            pack8(a0, a1), pack8(b0, b1), acc, 0, 0, 0);
    }
    __syncthreads();   // s_lds zeros visible

    // C/D layout (m89): col = lane&15, row = (lane>>4)*4 + reg
    const float scale = 0.03608439182435161f;  // 1/sqrt(768)
    #pragma unroll
    for (int r = 0; r < 4; ++r) {
        int lrow = g * 4 + r;
        size_t idx = ((size_t)(b * LL) + l0 + lrow) * WW + wcol;
        float m = mask[idx];
        m = fminf(fmaxf(m, 0.f), 1.f);
        float e = __expf(acc[r] * scale) * m;
        atomicAdd(&s_lds[lrow][label[idx]], e);
    }
    __syncthreads();

    if (t < LT * NL)
        s_out[(size_t)bid * (LT * NL) + t] = ((float*)s_lds)[t];
}

// ---------------------------------------------------------------------------
// K2: combine W-tile partials, normalize, 10-row epilogue + residual.
// Block = (b, 16 L-rows, 192 h-cols); grid 256, 192 threads (3 waves).
// ---------------------------------------------------------------------------
__global__ __launch_bounds__(192, 4) void combine_kernel(
    const float* __restrict__ s_in,     // [256][16][10]
    const float* __restrict__ hidden,   // [B,L,H]
    const float* __restrict__ emb_c,    // [10,H]
    float* __restrict__ out)            // [B,L,H]
{
    __shared__ float sp[LT][NL];
    __shared__ float inv[LT];
    const int t = threadIdx.x;
    const int bid = blockIdx.x;
    const int hq = bid & 3, lt = (bid >> 2) & 15, b = bid >> 6;
    const int l0 = lt * LT;
    const int h = hq * 192 + t;

    if (t < LT * NL) {
        size_t base = ((size_t)(b * 16 + lt)) * 4 * (LT * NL);  // wt=0 block
        float v = 0.f;
        #pragma unroll
        for (int wt = 0; wt < 4; ++wt) v += s_in[base + wt * (LT * NL) + t];
        ((float*)sp)[t] = v;
    }
    __syncthreads();
    if (t < LT) {
        float d = 1e-10f;
        #pragma unroll
        for (int k = 0; k < NL; ++k) d += sp[t][k];
        inv[t] = 1.f / d;
    }
    __syncthreads();

    float ec[NL];
    #pragma unroll
    for (int k = 0; k < NL; ++k) ec[k] = emb_c[k * HH + h];
    #pragma unroll
    for (int r = 0; r < LT; ++r) {
        size_t base = ((size_t)(b * LL) + l0 + r) * HH + h;
        float acc = 0.f;
        #pragma unroll
        for (int k = 0; k < NL; ++k) acc = fmaf(sp[r][k], ec[k], acc);
        out[base] = hidden[base] + acc * inv[r];
    }
}

extern "C" void kernel_launch(void* const* d_in, const int* in_sizes, int n_in,
                              void* d_out, int out_size, void* d_ws, size_t ws_size,
                              hipStream_t stream) {
    const int*   word_seq = (const int*)d_in[0];
    const float* hidden   = (const float*)d_in[1];
    const int*   label    = (const int*)d_in[2];
    const float* mask     = (const float*)d_in[3];
    const float* emb_a    = (const float*)d_in[4];
    const float* emb_c    = (const float*)d_in[5];
    float*       out      = (float*)d_out;

    float* s_out = (float*)d_ws;   // 256*160 fp32 = 160 KB scratch

    score_kernel<<<BB * 16 * 4, 256, 0, stream>>>(
        word_seq, hidden, emb_a, label, mask, s_out);
    combine_kernel<<<BB * 16 * 4, 192, 0, stream>>>(s_out, hidden, emb_c, out);
}